// Round 2
// baseline (82.143 us; speedup 1.0000x reference)
//
#include <hip/hip_runtime.h>
#include <hip/hip_bf16.h>
#include <stdint.h>

// Problem constants: A=2048 agents, H=128, G=8 (64 cells), NB=32, CELL=8
// pooled = (grid[A,64,128] flattened) @ W.T + b ; out masked by valid_i.

typedef __attribute__((ext_vector_type(4))) float f32x4;
typedef __attribute__((ext_vector_type(8))) short short8;

// workspace layout (bytes)
#define O_HB   0u          // bf16 hidden [2049][128]  (row 2048 = zeros, dummy target)
#define O_WB   1048576u    // bf16 W      [128][8192]
#define O_GRID 3145728u    // bf16 grid   [2048][8192]
#define O_PART 36700160u   // f32 partials [16][2048][128]
// total ~51 MB

__device__ __forceinline__ void gl_lds16(const void* g, void* l) {
  __builtin_amdgcn_global_load_lds((const __attribute__((address_space(1))) void*)g,
                                   (__attribute__((address_space(3))) void*)l, 16, 0, 0);
}

// ---------------- prep: f32 -> bf16 conversions ----------------
__global__ __launch_bounds__(256) void sp_prep(const float* __restrict__ hidden,
                                               const float* __restrict__ W,
                                               __hip_bfloat16* __restrict__ hb,
                                               __hip_bfloat16* __restrict__ wb) {
  int idx = blockIdx.x * 256 + threadIdx.x;
  const int HID4 = (2049 * 128) / 4;   // 65568 groups of 4
  const int W4   = (128 * 8192) / 4;   // 262144 groups of 4
  if (idx < HID4) {
    int e = idx * 4;
    float4 v = make_float4(0.f, 0.f, 0.f, 0.f);
    if (e < 2048 * 128) v = *reinterpret_cast<const float4*>(hidden + e);
    __hip_bfloat16 o0 = __float2bfloat16(v.x), o1 = __float2bfloat16(v.y);
    __hip_bfloat16 o2 = __float2bfloat16(v.z), o3 = __float2bfloat16(v.w);
    ushort4 pk;
    pk.x = *(unsigned short*)&o0; pk.y = *(unsigned short*)&o1;
    pk.z = *(unsigned short*)&o2; pk.w = *(unsigned short*)&o3;
    *reinterpret_cast<ushort4*>(hb + e) = pk;
  } else if (idx < HID4 + W4) {
    int e = (idx - HID4) * 4;
    float4 v = *reinterpret_cast<const float4*>(W + e);
    __hip_bfloat16 o0 = __float2bfloat16(v.x), o1 = __float2bfloat16(v.y);
    __hip_bfloat16 o2 = __float2bfloat16(v.z), o3 = __float2bfloat16(v.w);
    ushort4 pk;
    pk.x = *(unsigned short*)&o0; pk.y = *(unsigned short*)&o1;
    pk.z = *(unsigned short*)&o2; pk.w = *(unsigned short*)&o3;
    *reinterpret_cast<ushort4*>(wb + e) = pk;
  }
}

// ---------------- build: per-agent counting sort + register accumulate ----------------
__global__ __launch_bounds__(256) void sp_build(const float* __restrict__ pos,
                                                const int* __restrict__ mask,
                                                const __hip_bfloat16* __restrict__ hb,
                                                __hip_bfloat16* __restrict__ grid) {
  __shared__ __align__(8) uint16_t list[2304];   // padded cell-sorted j list (dummy = 2048)
  __shared__ uint8_t  binof[2048];
  __shared__ int hist[64];
  __shared__ int offs[65];
  __shared__ int cur[64];
  int t = threadIdx.x;
  int i = blockIdx.x;
  float pxi = pos[2 * i], pyi = pos[2 * i + 1];
  if (t < 64) hist[t] = 0;
  __syncthreads();
  const float2* pos2 = reinterpret_cast<const float2*>(pos);
  #pragma unroll
  for (int jj = 0; jj < 8; ++jj) {
    int j = t + jj * 256;
    float2 pj = pos2[j];
    float rx = pj.x - pxi, ry = pj.y - pyi;
    // NaN rel -> comparisons false -> invalid (matches reference)
    bool ok = (fabsf(rx) < 32.f) && (fabsf(ry) < 32.f) && (j != i) && (mask[j] != 0);
    int b = 255;
    if (ok) {
      int col = (int)floorf((rx + 32.f) * 0.125f);
      int row = (int)floorf((ry + 32.f) * 0.125f);
      col = min(max(col, 0), 7);
      row = min(max(row, 0), 7);
      b = row * 8 + col;
      atomicAdd(&hist[b], 1);
    }
    binof[j] = (uint8_t)b;
  }
  __syncthreads();
  if (t == 0) {  // serial prefix over 64 cells, segments padded to x4
    int a = 0;
    for (int c = 0; c < 64; ++c) { offs[c] = a; cur[c] = a; a += (hist[c] + 3) & ~3; }
    offs[64] = a;
  }
  __syncthreads();
  int total = offs[64];
  for (int k = t; k < total; k += 256) list[k] = 2048;  // dummy -> zero row of hb
  __syncthreads();
  #pragma unroll
  for (int jj = 0; jj < 8; ++jj) {
    int j = t + jj * 256;
    int b = binof[j];
    if (b != 255) { int k = atomicAdd(&cur[b], 1); list[k] = (uint16_t)j; }
  }
  __syncthreads();
  // accumulate: thread = h (128), par in {0,1} takes even/odd cells (no syncs needed)
  int h = t & 127;
  int par = t >> 7;
  const __hip_bfloat16* hbh = hb + h;
  for (int c = par; c < 64; c += 2) {
    int s0 = offs[c], e0 = offs[c + 1];
    float a0 = 0.f, a1 = 0.f, a2 = 0.f, a3 = 0.f;
    for (int k = s0; k < e0; k += 4) {
      unsigned long long q = *reinterpret_cast<const unsigned long long*>(&list[k]);
      int j0 = (int)(q & 0xffffu);
      int j1 = (int)((q >> 16) & 0xffffu);
      int j2 = (int)((q >> 32) & 0xffffu);
      int j3 = (int)((q >> 48) & 0xffffu);
      a0 += __bfloat162float(hbh[j0 << 7]);
      a1 += __bfloat162float(hbh[j1 << 7]);
      a2 += __bfloat162float(hbh[j2 << 7]);
      a3 += __bfloat162float(hbh[j3 << 7]);
    }
    grid[(size_t)((i << 6) + c) * 128 + h] = __float2bfloat16((a0 + a1) + (a2 + a3));
  }
}

// ---------------- gemm: [2048 x 8192] bf16 @ W[n][k] bf16 -> f32 partials (split-K 16) ----------------
// BM=64, BN=128, BK=64; 4 waves, wave-tile 32x64; mfma_f32_16x16x32_bf16
// LDS rows are 128 B = 8 x 16B granules; XOR-swizzle granule with (row&7):
// stage source pre-swizzled (linear LDS dest, per global_load_lds constraint), read with same XOR.
__global__ __launch_bounds__(256) void sp_gemm(const __hip_bfloat16* __restrict__ Ag,
                                               const __hip_bfloat16* __restrict__ Wb,
                                               float* __restrict__ part) {
  __shared__ __align__(16) char Asm[8192];    // A tile [64][64] bf16
  __shared__ __align__(16) char Bsm[16384];   // B tile [128][64] bf16 (n-major)
  int t = threadIdx.x;
  int lane = t & 63;
  int w = t >> 6;
  int wm = w >> 1, wn = w & 1;
  int bx = blockIdx.x;
  int mt = bx & 31;     // 32 M-tiles of 64 rows
  int sp = bx >> 5;     // 16 K-splits of 512
  int i0 = mt * 64;
  long kbase = (long)sp * 512 * 2;  // byte offset of K-chunk within a row
  const char* Agc = (const char*)Ag;
  const char* Wbc = (const char*)Wb;
  f32x4 acc[2][4] = {};
  for (int st = 0; st < 8; ++st) {   // 8 K-steps of 64
    long kb = kbase + st * 128;
    #pragma unroll
    for (int q = 0; q < 2; ++q) {    // A: 8 KB
      int o = (q * 256 + t) * 16;
      int r = o >> 7;
      int sc = (o & 127) ^ ((r & 7) << 4);
      gl_lds16(Agc + (long)(i0 + r) * 16384 + kb + sc, Asm + o);
    }
    #pragma unroll
    for (int q = 0; q < 4; ++q) {    // B: 16 KB
      int o = (q * 256 + t) * 16;
      int r = o >> 7;
      int sc = (o & 127) ^ ((r & 7) << 4);
      gl_lds16(Wbc + (long)r * 16384 + kb + sc, Bsm + o);
    }
    __syncthreads();
    short8 af[2][2], bfr[4][2];
    #pragma unroll
    for (int fr = 0; fr < 2; ++fr)
      #pragma unroll
      for (int ks = 0; ks < 2; ++ks) {
        int r = wm * 32 + fr * 16 + (lane & 15);
        int g = ks * 4 + (lane >> 4);
        int byt = r * 128 + ((g ^ (r & 7)) << 4);
        af[fr][ks] = *reinterpret_cast<const short8*>(Asm + byt);
      }
    #pragma unroll
    for (int fc = 0; fc < 4; ++fc)
      #pragma unroll
      for (int ks = 0; ks < 2; ++ks) {
        int n = wn * 64 + fc * 16 + (lane & 15);
        int g = ks * 4 + (lane >> 4);
        int byt = n * 128 + ((g ^ (n & 7)) << 4);
        bfr[fc][ks] = *reinterpret_cast<const short8*>(Bsm + byt);
      }
    #pragma unroll
    for (int fr = 0; fr < 2; ++fr)
      #pragma unroll
      for (int fc = 0; fc < 4; ++fc)
        #pragma unroll
        for (int ks = 0; ks < 2; ++ks)
          acc[fr][fc] = __builtin_amdgcn_mfma_f32_16x16x32_bf16(af[fr][ks], bfr[fc][ks],
                                                                acc[fr][fc], 0, 0, 0);
    __syncthreads();
  }
  float* p = part + (long)sp * 262144;
  #pragma unroll
  for (int fr = 0; fr < 2; ++fr)
    #pragma unroll
    for (int fc = 0; fc < 4; ++fc)
      #pragma unroll
      for (int r4 = 0; r4 < 4; ++r4) {
        int ii = i0 + wm * 32 + fr * 16 + (lane >> 4) * 4 + r4;  // C/D: row=(lane>>4)*4+reg
        int nn = wn * 64 + fc * 16 + (lane & 15);                 // C/D: col=lane&15
        p[(long)ii * 128 + nn] = acc[fr][fc][r4];
      }
}

// ---------------- reduce: sum 16 partials + bias, apply valid_i mask ----------------
__global__ __launch_bounds__(256) void sp_reduce(const float* __restrict__ part,
                                                 const float* __restrict__ bias,
                                                 const float* __restrict__ pos,
                                                 const int* __restrict__ mask,
                                                 float* __restrict__ out) {
  int g = blockIdx.x * 256 + threadIdx.x;  // 0..262143
  int i = g >> 7, n = g & 127;
  float acc = bias[n];
  #pragma unroll
  for (int s = 0; s < 16; ++s) acc += part[(long)s * 262144 + g];
  float px = pos[2 * i], py = pos[2 * i + 1];
  bool vi = (mask[i] != 0) && (px == px) && (py == py);  // mask & ~isnan(pos).any
  out[g] = vi ? acc : 0.f;
}

extern "C" void kernel_launch(void* const* d_in, const int* in_sizes, int n_in,
                              void* d_out, int out_size, void* d_ws, size_t ws_size,
                              hipStream_t stream) {
  const float* hidden  = (const float*)d_in[0];
  const float* pos     = (const float*)d_in[1];
  const int*   mask    = (const int*)d_in[2];   // bool input -> int32 per harness contract
  const float* W       = (const float*)d_in[3];
  const float* bias    = (const float*)d_in[4];
  char* ws = (char*)d_ws;
  __hip_bfloat16* hb   = (__hip_bfloat16*)(ws + O_HB);
  __hip_bfloat16* wb   = (__hip_bfloat16*)(ws + O_WB);
  __hip_bfloat16* grid = (__hip_bfloat16*)(ws + O_GRID);
  float* part          = (float*)(ws + O_PART);
  float* out           = (float*)d_out;

  sp_prep<<<1281, 256, 0, stream>>>(hidden, W, hb, wb);
  sp_build<<<2048, 256, 0, stream>>>(pos, mask, hb, grid);
  sp_gemm<<<512, 256, 0, stream>>>(grid, wb, part);
  sp_reduce<<<1024, 256, 0, stream>>>(part, bias, pos, mask, out);
}

// Round 3
// 64.068 us; speedup vs baseline: 1.2821x; 1.2821x over previous
//
#include <hip/hip_runtime.h>
#include <hip/hip_bf16.h>
#include <stdint.h>

// Problem constants: A=2048 agents, H=128, G=8 (64 cells), NB=32, CELL=8
// pooled = (grid[A,64,128] flattened) @ W.T + b ; out masked by valid_i.

typedef __attribute__((ext_vector_type(4))) float f32x4;
typedef __attribute__((ext_vector_type(8))) short short8;

// workspace layout (bytes)
#define O_HB   0u          // bf16 hidden [2049][128]  (row 2048 = zeros, dummy target)
#define O_WB   1048576u    // bf16 W      [128][8192]
#define O_GRID 3145728u    // bf16 grid   [2048][8192]
#define O_PART 36700160u   // f32 partials [16][2048][128]
// total ~51 MB

__device__ __forceinline__ void gl_lds16(const void* g, void* l) {
  __builtin_amdgcn_global_load_lds((const __attribute__((address_space(1))) void*)g,
                                   (__attribute__((address_space(3))) void*)l, 16, 0, 0);
}

// ---------------- prep: f32 -> bf16 conversions ----------------
__global__ __launch_bounds__(256) void sp_prep(const float* __restrict__ hidden,
                                               const float* __restrict__ W,
                                               __hip_bfloat16* __restrict__ hb,
                                               __hip_bfloat16* __restrict__ wb) {
  int idx = blockIdx.x * 256 + threadIdx.x;
  const int HID4 = (2049 * 128) / 4;   // 65568 groups of 4
  const int W4   = (128 * 8192) / 4;   // 262144 groups of 4
  if (idx < HID4) {
    int e = idx * 4;
    float4 v = make_float4(0.f, 0.f, 0.f, 0.f);
    if (e < 2048 * 128) v = *reinterpret_cast<const float4*>(hidden + e);
    __hip_bfloat16 o0 = __float2bfloat16(v.x), o1 = __float2bfloat16(v.y);
    __hip_bfloat16 o2 = __float2bfloat16(v.z), o3 = __float2bfloat16(v.w);
    ushort4 pk;
    pk.x = *(unsigned short*)&o0; pk.y = *(unsigned short*)&o1;
    pk.z = *(unsigned short*)&o2; pk.w = *(unsigned short*)&o3;
    *reinterpret_cast<ushort4*>(hb + e) = pk;
  } else if (idx < HID4 + W4) {
    int e = (idx - HID4) * 4;
    float4 v = *reinterpret_cast<const float4*>(W + e);
    __hip_bfloat16 o0 = __float2bfloat16(v.x), o1 = __float2bfloat16(v.y);
    __hip_bfloat16 o2 = __float2bfloat16(v.z), o3 = __float2bfloat16(v.w);
    ushort4 pk;
    pk.x = *(unsigned short*)&o0; pk.y = *(unsigned short*)&o1;
    pk.z = *(unsigned short*)&o2; pk.w = *(unsigned short*)&o3;
    *reinterpret_cast<ushort4*>(wb + e) = pk;
  }
}

// ---------------- build: per-agent counting sort + dword-gather accumulate ----------------
// 256 threads. Phase A: bin all 2048 j's (bins kept in VGPRs). Phase B: wave-0
// shfl prefix scan over padded cell counts. Phase C: scatter j's into cell-sorted
// list. Phase D: lane l owns columns {2l,2l+1}; par=t>>6 takes cells c%4==par;
// each hidden row is one coalesced 256B wave-load (dword/lane), bf16x2 unpacked
// and accumulated in f32.
__global__ __launch_bounds__(256) void sp_build(const float* __restrict__ pos,
                                                const int* __restrict__ mask,
                                                const __hip_bfloat16* __restrict__ hb,
                                                __hip_bfloat16* __restrict__ grid) {
  __shared__ __align__(8) uint16_t list[2304];   // padded cell-sorted j list (dummy = 2048)
  __shared__ int hist[64];
  __shared__ int offs[65];
  __shared__ int cur[64];
  int t = threadIdx.x;
  int i = blockIdx.x;
  float pxi = pos[2 * i], pyi = pos[2 * i + 1];
  if (t < 64) hist[t] = 0;
  __syncthreads();
  const float2* pos2 = reinterpret_cast<const float2*>(pos);
  int bins[8];
  #pragma unroll
  for (int jj = 0; jj < 8; ++jj) {
    int j = t + jj * 256;
    float2 pj = pos2[j];
    float rx = pj.x - pxi, ry = pj.y - pyi;
    // NaN rel -> comparisons false -> invalid (matches reference)
    bool ok = (fabsf(rx) < 32.f) && (fabsf(ry) < 32.f) && (j != i) && (mask[j] != 0);
    int b = -1;
    if (ok) {
      int col = (int)floorf((rx + 32.f) * 0.125f);
      int row = (int)floorf((ry + 32.f) * 0.125f);
      col = min(max(col, 0), 7);
      row = min(max(row, 0), 7);
      b = row * 8 + col;
      atomicAdd(&hist[b], 1);
    }
    bins[jj] = b;
  }
  // fill list with dummy before scatter (entire buffer; padding slots stay dummy)
  #pragma unroll
  for (int q = 0; q < 9; ++q) {
    int k = t + q * 256;
    if (k < 2304) list[k] = 2048;
  }
  __syncthreads();
  if (t < 64) {  // wave-0 parallel scan over padded cell sizes
    int padded = (hist[t] + 3) & ~3;
    int x = padded;
    #pragma unroll
    for (int d = 1; d < 64; d <<= 1) {
      int y = __shfl_up(x, d);
      if (t >= d) x += y;
    }
    offs[t + 1] = x;          // inclusive -> start of next cell
    cur[t] = x - padded;      // exclusive -> start of this cell
    if (t == 0) offs[0] = 0;
  }
  __syncthreads();
  #pragma unroll
  for (int jj = 0; jj < 8; ++jj) {
    int j = t + jj * 256;
    int b = bins[jj];
    if (b >= 0) { int k = atomicAdd(&cur[b], 1); list[k] = (uint16_t)j; }
  }
  __syncthreads();
  // Phase D: accumulate. lane l -> columns 2l,2l+1 ; par -> cells c%4
  int l = t & 63;
  int par = t >> 6;
  const uint32_t* hbw = reinterpret_cast<const uint32_t*>(hb);  // row j: hbw[j*64 + l]
  for (int c = par; c < 64; c += 4) {
    int s0 = offs[c], e0 = offs[c + 1];
    float a0x = 0.f, a0y = 0.f, a1x = 0.f, a1y = 0.f;
    float a2x = 0.f, a2y = 0.f, a3x = 0.f, a3y = 0.f;
    for (int k = s0; k < e0; k += 4) {
      unsigned long long q = *reinterpret_cast<const unsigned long long*>(&list[k]);
      int j0 = (int)(q & 0xffffu);
      int j1 = (int)((q >> 16) & 0xffffu);
      int j2 = (int)((q >> 32) & 0xffffu);
      int j3 = (int)((q >> 48) & 0xffffu);
      uint32_t w0 = hbw[(j0 << 6) + l];
      uint32_t w1 = hbw[(j1 << 6) + l];
      uint32_t w2 = hbw[(j2 << 6) + l];
      uint32_t w3 = hbw[(j3 << 6) + l];
      union { uint32_t u; float f; } lo0{w0 << 16}, hi0{w0 & 0xffff0000u};
      union { uint32_t u; float f; } lo1{w1 << 16}, hi1{w1 & 0xffff0000u};
      union { uint32_t u; float f; } lo2{w2 << 16}, hi2{w2 & 0xffff0000u};
      union { uint32_t u; float f; } lo3{w3 << 16}, hi3{w3 & 0xffff0000u};
      a0x += lo0.f; a0y += hi0.f;
      a1x += lo1.f; a1y += hi1.f;
      a2x += lo2.f; a2y += hi2.f;
      a3x += lo3.f; a3y += hi3.f;
    }
    float rx = (a0x + a1x) + (a2x + a3x);
    float ry = (a0y + a1y) + (a2y + a3y);
    __hip_bfloat16 b0 = __float2bfloat16(rx), b1 = __float2bfloat16(ry);
    uint32_t pk = ((uint32_t)(*(unsigned short*)&b1) << 16) | (*(unsigned short*)&b0);
    *reinterpret_cast<uint32_t*>(
        reinterpret_cast<char*>(grid) + ((size_t)((i << 6) + c) * 256 + (size_t)l * 4)) = pk;
  }
}

// ---------------- gemm: [2048 x 8192] bf16 @ W[n][k] bf16 -> f32 partials (split-K 16) ----------------
// BM=64, BN=128, BK=64; 4 waves, wave-tile 32x64; mfma_f32_16x16x32_bf16
// LDS rows are 128 B = 8 x 16B granules; XOR-swizzle granule with (row&7):
// stage source pre-swizzled (linear LDS dest, per global_load_lds constraint), read with same XOR.
__global__ __launch_bounds__(256) void sp_gemm(const __hip_bfloat16* __restrict__ Ag,
                                               const __hip_bfloat16* __restrict__ Wb,
                                               float* __restrict__ part) {
  __shared__ __align__(16) char Asm[8192];    // A tile [64][64] bf16
  __shared__ __align__(16) char Bsm[16384];   // B tile [128][64] bf16 (n-major)
  int t = threadIdx.x;
  int lane = t & 63;
  int w = t >> 6;
  int wm = w >> 1, wn = w & 1;
  int bx = blockIdx.x;
  int mt = bx & 31;     // 32 M-tiles of 64 rows
  int sp = bx >> 5;     // 16 K-splits of 512
  int i0 = mt * 64;
  long kbase = (long)sp * 512 * 2;  // byte offset of K-chunk within a row
  const char* Agc = (const char*)Ag;
  const char* Wbc = (const char*)Wb;
  f32x4 acc[2][4] = {};
  for (int st = 0; st < 8; ++st) {   // 8 K-steps of 64
    long kb = kbase + st * 128;
    #pragma unroll
    for (int q = 0; q < 2; ++q) {    // A: 8 KB
      int o = (q * 256 + t) * 16;
      int r = o >> 7;
      int sc = (o & 127) ^ ((r & 7) << 4);
      gl_lds16(Agc + (long)(i0 + r) * 16384 + kb + sc, Asm + o);
    }
    #pragma unroll
    for (int q = 0; q < 4; ++q) {    // B: 16 KB
      int o = (q * 256 + t) * 16;
      int r = o >> 7;
      int sc = (o & 127) ^ ((r & 7) << 4);
      gl_lds16(Wbc + (long)r * 16384 + kb + sc, Bsm + o);
    }
    __syncthreads();
    short8 af[2][2], bfr[4][2];
    #pragma unroll
    for (int fr = 0; fr < 2; ++fr)
      #pragma unroll
      for (int ks = 0; ks < 2; ++ks) {
        int r = wm * 32 + fr * 16 + (lane & 15);
        int g = ks * 4 + (lane >> 4);
        int byt = r * 128 + ((g ^ (r & 7)) << 4);
        af[fr][ks] = *reinterpret_cast<const short8*>(Asm + byt);
      }
    #pragma unroll
    for (int fc = 0; fc < 4; ++fc)
      #pragma unroll
      for (int ks = 0; ks < 2; ++ks) {
        int n = wn * 64 + fc * 16 + (lane & 15);
        int g = ks * 4 + (lane >> 4);
        int byt = n * 128 + ((g ^ (n & 7)) << 4);
        bfr[fc][ks] = *reinterpret_cast<const short8*>(Bsm + byt);
      }
    #pragma unroll
    for (int fr = 0; fr < 2; ++fr)
      #pragma unroll
      for (int fc = 0; fc < 4; ++fc)
        #pragma unroll
        for (int ks = 0; ks < 2; ++ks)
          acc[fr][fc] = __builtin_amdgcn_mfma_f32_16x16x32_bf16(af[fr][ks], bfr[fc][ks],
                                                                acc[fr][fc], 0, 0, 0);
    __syncthreads();
  }
  float* p = part + (long)sp * 262144;
  #pragma unroll
  for (int fr = 0; fr < 2; ++fr)
    #pragma unroll
    for (int fc = 0; fc < 4; ++fc)
      #pragma unroll
      for (int r4 = 0; r4 < 4; ++r4) {
        int ii = i0 + wm * 32 + fr * 16 + (lane >> 4) * 4 + r4;  // C/D: row=(lane>>4)*4+reg
        int nn = wn * 64 + fc * 16 + (lane & 15);                 // C/D: col=lane&15
        p[(long)ii * 128 + nn] = acc[fr][fc][r4];
      }
}

// ---------------- reduce: sum 16 partials + bias, apply valid_i mask ----------------
__global__ __launch_bounds__(256) void sp_reduce(const float* __restrict__ part,
                                                 const float* __restrict__ bias,
                                                 const float* __restrict__ pos,
                                                 const int* __restrict__ mask,
                                                 float* __restrict__ out) {
  int g = blockIdx.x * 256 + threadIdx.x;  // 0..262143
  int i = g >> 7, n = g & 127;
  float acc = bias[n];
  #pragma unroll
  for (int s = 0; s < 16; ++s) acc += part[(long)s * 262144 + g];
  float px = pos[2 * i], py = pos[2 * i + 1];
  bool vi = (mask[i] != 0) && (px == px) && (py == py);  // mask & ~isnan(pos).any
  out[g] = vi ? acc : 0.f;
}

extern "C" void kernel_launch(void* const* d_in, const int* in_sizes, int n_in,
                              void* d_out, int out_size, void* d_ws, size_t ws_size,
                              hipStream_t stream) {
  const float* hidden  = (const float*)d_in[0];
  const float* pos     = (const float*)d_in[1];
  const int*   mask    = (const int*)d_in[2];   // bool input -> int32 per harness contract
  const float* W       = (const float*)d_in[3];
  const float* bias    = (const float*)d_in[4];
  char* ws = (char*)d_ws;
  __hip_bfloat16* hb   = (__hip_bfloat16*)(ws + O_HB);
  __hip_bfloat16* wb   = (__hip_bfloat16*)(ws + O_WB);
  __hip_bfloat16* grid = (__hip_bfloat16*)(ws + O_GRID);
  float* part          = (float*)(ws + O_PART);
  float* out           = (float*)d_out;

  sp_prep<<<1281, 256, 0, stream>>>(hidden, W, hb, wb);
  sp_build<<<2048, 256, 0, stream>>>(pos, mask, hb, grid);
  sp_gemm<<<512, 256, 0, stream>>>(grid, wb, part);
  sp_reduce<<<1024, 256, 0, stream>>>(part, bias, pos, mask, out);
}